// Round 3
// baseline (1077.428 us; speedup 1.0000x reference)
//
#include <hip/hip_runtime.h>
#include <math.h>

#define HID 64
#define G4 256
#define TSTEPS 256
#define BATCH 64
#define MTOT 16384
#define NVOCAB 8000

typedef float fvec4 __attribute__((ext_vector_type(4)));

__device__ __forceinline__ float tanh_s(float x){
    float ax = fabsf(x);
    float e = __expf(-2.0f*ax);
    float t = (1.0f - e)/(1.0f + e);
    return x >= 0.f ? t : -t;
}

// dot of 64-float register row (16 float4) with 64-float LDS vector (broadcast reads)
__device__ __forceinline__ float dot64(const float4* w, const float4* h){
    float s0=0.f, s1=0.f, s2=0.f, s3=0.f;
    #pragma unroll
    for (int i = 0; i < 16; i += 4){
        float4 h0 = h[i+0];
        float4 h1 = h[i+1];
        float4 h2 = h[i+2];
        float4 h3 = h[i+3];
        s0 = fmaf(w[i+0].x,h0.x,s0); s0 = fmaf(w[i+0].y,h0.y,s0);
        s0 = fmaf(w[i+0].z,h0.z,s0); s0 = fmaf(w[i+0].w,h0.w,s0);
        s1 = fmaf(w[i+1].x,h1.x,s1); s1 = fmaf(w[i+1].y,h1.y,s1);
        s1 = fmaf(w[i+1].z,h1.z,s1); s1 = fmaf(w[i+1].w,h1.w,s1);
        s2 = fmaf(w[i+2].x,h2.x,s2); s2 = fmaf(w[i+2].y,h2.y,s2);
        s2 = fmaf(w[i+2].z,h2.z,s2); s2 = fmaf(w[i+2].w,h2.w,s2);
        s3 = fmaf(w[i+3].x,h3.x,s3); s3 = fmaf(w[i+3].y,h3.y,s3);
        s3 = fmaf(w[i+3].z,h3.z,s3); s3 = fmaf(w[i+3].w,h3.w,s3);
    }
    return (s0+s1) + (s2+s3);
}

__global__ void bsum_k(const float* __restrict__ a, const float* __restrict__ b, float* __restrict__ o, int n){
    int i = blockIdx.x*256 + threadIdx.x;
    if (i < n) o[i] = a[i] + b[i];
}

// C[M][N] = A[M][KTOT] * B[N][KTOT]^T + bias[N]; B row-major [N][K].
// 128x128 tile, 8x8 micro-tile/thread, K-major LDS tiles, BK templated.
template<int KTOT, int BK, int MINB, bool NTSTORE>
__global__ __launch_bounds__(256, MINB) void gemm_bias_nt(
    const float* __restrict__ A, const float* __restrict__ B,
    const float* __restrict__ bias, float* __restrict__ C,
    int M, int N)
{
    __shared__ float As[BK][132];
    __shared__ float Bs[BK][132];
    const int tid = threadIdx.x;
    const int tx = tid & 15;
    const int ty = tid >> 4;
    const int m0 = blockIdx.y * 128;
    const int n0 = blockIdx.x * 128;

    constexpr int RPP = 1024 / BK;     // rows per staging pass
    constexpr int NPASS = 128 / RPP;
    const int rl = tid & (RPP-1);
    const int k4 = (tid / RPP) * 4;

    float4 acc0[8], acc1[8];
    #pragma unroll
    for (int i = 0; i < 8; i++){
        acc0[i] = make_float4(0.f,0.f,0.f,0.f);
        acc1[i] = make_float4(0.f,0.f,0.f,0.f);
    }

    for (int k0 = 0; k0 < KTOT; k0 += BK){
        #pragma unroll
        for (int it = 0; it < NPASS; it++){
            int r = it*RPP + rl;
            float4 va = *(const float4*)(A + (size_t)(m0+r)*KTOT + k0 + k4);
            As[k4+0][r] = va.x; As[k4+1][r] = va.y;
            As[k4+2][r] = va.z; As[k4+3][r] = va.w;
            float4 vb = make_float4(0.f,0.f,0.f,0.f);
            if (n0 + r < N)
                vb = *(const float4*)(B + (size_t)(n0+r)*KTOT + k0 + k4);
            Bs[k4+0][r] = vb.x; Bs[k4+1][r] = vb.y;
            Bs[k4+2][r] = vb.z; Bs[k4+3][r] = vb.w;
        }
        __syncthreads();

        #pragma unroll 8
        for (int k = 0; k < BK; k++){
            float4 a0 = *(const float4*)&As[k][ty*8];
            float4 a1 = *(const float4*)&As[k][ty*8 + 4];
            float4 b0 = *(const float4*)&Bs[k][tx*4];
            float4 b1 = *(const float4*)&Bs[k][64 + tx*4];
            float av[8] = {a0.x,a0.y,a0.z,a0.w,a1.x,a1.y,a1.z,a1.w};
            #pragma unroll
            for (int i = 0; i < 8; i++){
                acc0[i].x = fmaf(av[i], b0.x, acc0[i].x);
                acc0[i].y = fmaf(av[i], b0.y, acc0[i].y);
                acc0[i].z = fmaf(av[i], b0.z, acc0[i].z);
                acc0[i].w = fmaf(av[i], b0.w, acc0[i].w);
                acc1[i].x = fmaf(av[i], b1.x, acc1[i].x);
                acc1[i].y = fmaf(av[i], b1.y, acc1[i].y);
                acc1[i].z = fmaf(av[i], b1.z, acc1[i].z);
                acc1[i].w = fmaf(av[i], b1.w, acc1[i].w);
            }
        }
        __syncthreads();
    }

    const int v0a = n0 + tx*4;
    const int v0b = n0 + 64 + tx*4;
    float4 ba = make_float4(0.f,0.f,0.f,0.f);
    float4 bb = make_float4(0.f,0.f,0.f,0.f);
    if (v0a < N) ba = *(const float4*)(bias + v0a);
    if (v0b < N) bb = *(const float4*)(bias + v0b);
    #pragma unroll
    for (int i = 0; i < 8; i++){
        int m = m0 + ty*8 + i;
        float* crow = C + (size_t)m*N;
        if (v0a < N){
            fvec4 r;
            r.x = acc0[i].x + ba.x; r.y = acc0[i].y + ba.y;
            r.z = acc0[i].z + ba.z; r.w = acc0[i].w + ba.w;
            if (NTSTORE) __builtin_nontemporal_store(r, (fvec4*)(crow + v0a));
            else *(fvec4*)(crow + v0a) = r;
        }
        if (v0b < N){
            fvec4 r;
            r.x = acc1[i].x + bb.x; r.y = acc1[i].y + bb.y;
            r.z = acc1[i].z + bb.z; r.w = acc1[i].w + bb.w;
            if (NTSTORE) __builtin_nontemporal_store(r, (fvec4*)(crow + v0b));
            else *(fvec4*)(crow + v0b) = r;
        }
    }
}

// Fused 2-layer LSTM: one block per batch element, 512 threads.
// Waves 0-3: layer 0 (reads xp0).  Waves 4-7: layer 1, lagging one step,
// computing its x-projection (Wih1 . h1[t]) inline from registers.
// One barrier per pipeline step. h2 history kept in LDS, bulk-flushed at end.
__global__ __launch_bounds__(512, 2) void lstm_fused(
    const float* __restrict__ XP,     // xp0: [B][T][256]
    const float* __restrict__ Whh0,   // [256][64]
    const float* __restrict__ Wih1,   // [256][64]
    const float* __restrict__ Whh1,   // [256][64]
    const float* __restrict__ bih1,
    const float* __restrict__ bhh1,
    float* __restrict__ H2out)        // [B][T][64]
{
    const int b = blockIdx.x;
    const int tid = threadIdx.x;
    const bool L1g = tid >= 256;
    const int t256 = tid & 255;
    const int lane = t256 & 63;
    const int w4 = t256 >> 6;               // wave index within group (0..3)
    const int g  = lane & 3;                // 0:i 1:f 2:g 3:o
    const int j  = w4*16 + (lane >> 2);     // h index 0..63
    const int row = g*64 + j;
    const bool gb0 = (g & 1) != 0;
    const bool gb1 = (g & 2) != 0;
    const bool is_g = (g == 2);

    __shared__ __align__(16) float h1r[8][HID];            // ring buffer of h1 state
    __shared__ __align__(16) float hist2[TSTEPS+1][HID];   // full h2 history

    float4 wA[16];         // L0: Whh0 row ; L1: Whh1 row
    float4 wB[16];         // L1 only: Wih1 row
    float bias1 = 0.f;
    if (!L1g){
        const float4* wr = (const float4*)(Whh0 + (size_t)row*HID);
        #pragma unroll
        for (int i = 0; i < 16; i++) wA[i] = wr[i];
    } else {
        const float4* wr = (const float4*)(Whh1 + (size_t)row*HID);
        const float4* wi = (const float4*)(Wih1 + (size_t)row*HID);
        #pragma unroll
        for (int i = 0; i < 16; i++){ wA[i] = wr[i]; wB[i] = wi[i]; }
        bias1 = bih1[row] + bhh1[row];
    }

    if (tid < HID) h1r[0][tid] = 0.f;
    else if (tid < 2*HID) hist2[0][tid - HID] = 0.f;
    __syncthreads();

    const float* xprow = XP + (size_t)b*TSTEPS*G4 + row;
    float xn0 = 0.f, xn1 = 0.f;
    if (!L1g){ xn0 = xprow[0]; xn1 = xprow[G4]; }
    float c = 0.f;

    for (int t = 0; t <= TSTEPS; t++){
        const bool active = L1g ? (t >= 1) : (t < TSTEPS);
        if (active){
            float a;
            if (!L1g){
                a = xn0;
                xn0 = xn1;
                if (t + 2 < TSTEPS) xn1 = xprow[(size_t)(t+2)*G4];
                a += dot64(wA, (const float4*)h1r[t & 7]);
            } else {
                // computes h2[t-1]: needs h1[t-1] (slot t&7) and h2[t-2] (hist2[t-1])
                a = bias1
                  + dot64(wB, (const float4*)h1r[t & 7])
                  + dot64(wA, (const float4*)hist2[t-1]);
            }

            float aa = is_g ? 2.f*a : a;
            float sg = 1.f/(1.f + __expf(-aa));
            float act = is_g ? 2.f*sg - 1.f : sg;

            float a1v = __shfl_xor(act, 1, 64);
            float a2v = __shfl_xor(act, 2, 64);
            float a3v = __shfl_xor(act, 3, 64);
            float x0 = gb0 ? a1v : act;
            float x1 = gb0 ? act : a1v;
            float x2 = gb0 ? a3v : a2v;
            float x3 = gb0 ? a2v : a3v;
            float ig = gb1 ? x2 : x0;
            float fg = gb1 ? x3 : x1;
            float gg = gb1 ? x0 : x2;
            float og = gb1 ? x1 : x3;

            c = fmaf(fg, c, ig*gg);
            float hn = og * tanh_s(c);
            if (g == 0){
                if (!L1g) h1r[(t+1) & 7][j] = hn;
                else      hist2[t][j] = hn;     // h2[t-1]
            }
        }
        __syncthreads();
    }

    // hist2[1..256] = h2[0..255] -> coalesced bulk flush
    const float4* s4 = (const float4*)&hist2[1][0];
    float4* o4 = (float4*)(H2out + (size_t)b*TSTEPS*HID);
    #pragma unroll 4
    for (int i = tid; i < TSTEPS*HID/4; i += 512) o4[i] = s4[i];
}

extern "C" void kernel_launch(void* const* d_in, const int* in_sizes, int n_in,
                              void* d_out, int out_size, void* d_ws, size_t ws_size,
                              hipStream_t stream)
{
    const float* x    = (const float*)d_in[0];
    const float* Wih0 = (const float*)d_in[1];
    const float* Whh0 = (const float*)d_in[2];
    const float* bih0 = (const float*)d_in[3];
    const float* bhh0 = (const float*)d_in[4];
    const float* Wih1 = (const float*)d_in[5];
    const float* Whh1 = (const float*)d_in[6];
    const float* bih1 = (const float*)d_in[7];
    const float* bhh1 = (const float*)d_in[8];
    const float* Wl   = (const float*)d_in[9];
    const float* bl   = (const float*)d_in[10];
    float* out = (float*)d_out;

    float* ws  = (float*)d_ws;
    float* bs0 = ws;                  // 256
    float* xp0 = bs0 + 256;           // [16384][256]
    float* h2  = xp0 + 4194304;       // [16384][64]

    bsum_k<<<1, 256, 0, stream>>>(bih0, bhh0, bs0, 256);

    // layer 0 x-projection: xp0 = x @ Wih0^T + (bih0+bhh0)
    gemm_bias_nt<256,64,2,false><<<dim3(2,128), 256, 0, stream>>>(x, Wih0, bs0, xp0, MTOT, 256);

    // fused: lstm0 -> (inline xp1) -> lstm1
    lstm_fused<<<BATCH, 512, 0, stream>>>(xp0, Whh0, Wih1, Whh1, bih1, bhh1, h2);

    // vocab projection: out = h2 @ Wl^T + bl  (streaming output -> nontemporal)
    gemm_bias_nt<64,32,3,true><<<dim3(63,128), 256, 0, stream>>>(h2, Wl, bl, out, MTOT, NVOCAB);
}